// Round 2
// baseline (36894.757 us; speedup 1.0000x reference)
//
#include <hip/hip_runtime.h>
#include <hip/hip_fp16.h>
#include <math.h>

#define BB 32
#define LAV 256
#define LCV 256
#define DV 300
#define HV 256
#define G3 768   // 3*H

// ---------- fast math helpers ----------
static __device__ __forceinline__ float rcp_(float x) { return __builtin_amdgcn_rcpf(x); }
static __device__ __forceinline__ float sigm(float x) { return rcp_(1.f + __expf(-x)); }
static __device__ __forceinline__ float tanh_(float x) { return 1.f - 2.f * rcp_(1.f + __expf(2.f * x)); }

// ---------- weight packing ----------
// case0: WT_a  [300][768] = W_ih_a^T
// case1: WT_cx [300][768] = W_ih_c[:, :300]^T
// case2: Whha4 [64][768][4] float: quad-k pack of W_hh_a^T (anchor, fp32)
// case3: Wq_h  [8][256][32] half: per-slice Wq columns (q = h @ Wq)
// case4: Wg_h  [8][64][768] half: per-slice candidate gate weights, k-major
//        k<32 -> h-dim (W_hh_c col), k>=32 -> ctx-dim (W_ih_c col 300+)
__global__ void prep_pack(const float* __restrict__ W_ih_a, const float* __restrict__ W_ih_c,
                          const float* __restrict__ W_hh_a, const float* __restrict__ W_hh_c,
                          const float* __restrict__ Wq,
                          float* __restrict__ WT_a, float* __restrict__ WT_cx,
                          float* __restrict__ Whha4, __half* __restrict__ Wq_h,
                          __half* __restrict__ Wg_h)
{
    int i = blockIdx.x * 256 + threadIdx.x;
    switch (blockIdx.y) {
    case 0: if (i < 300 * 768) { int k = i / 768, n = i % 768; WT_a[i] = W_ih_a[n * 300 + k]; } break;
    case 1: if (i < 300 * 768) { int k = i / 768, n = i % 768; WT_cx[i] = W_ih_c[n * 556 + k]; } break;
    case 2: if (i < 64 * 768 * 4) { int cc = i & 3, j = (i >> 2) % 768, k4 = (i >> 2) / 768;
            Whha4[i] = W_hh_a[j * 256 + k4 * 4 + cc]; } break;
    case 3: if (i < 8 * 256 * 32) { int mm = i & 31, k = (i >> 5) & 255, cs = i >> 13;
            Wq_h[i] = __float2half(Wq[k * 256 + cs * 32 + mm]); } break;
    case 4: if (i < 8 * 64 * 768) { int j = i % 768, kk = (i / 768) & 63, cs = i / (64 * 768);
            float v = (kk < 32) ? W_hh_c[j * 256 + cs * 32 + kk]
                                : W_ih_c[j * 556 + 300 + cs * 32 + (kk - 32)];
            Wg_h[i] = __float2half(v); } break;
    }
}

__global__ void zero_sync(unsigned* __restrict__ syncb) {
    if (threadIdx.x < 80) syncb[threadIdx.x] = 0u;
}

// ---------- tiled fp32 GEMM ----------
// MODE 0: Cout[m*N+n] = acc + bias[n]                  (GI precompute)
// MODE 1: Cout[(b*256+h)*256+l] = tanh(acc)            (keys -> T, [b][h][l])
template <int MODE>
__global__ __launch_bounds__(256) void gemm_tile(
    const float* __restrict__ X, const int* __restrict__ gidx, int ldx,
    const float* __restrict__ Wt, int K, int Nn,
    const float* __restrict__ bias, float* __restrict__ Cout)
{
    __shared__ __align__(16) float As[32][68];
    __shared__ __align__(16) float Bs[32][68];
    __shared__ int toks[64];
    int tid = threadIdx.x;
    int m0 = blockIdx.x * 64, n0 = blockIdx.y * 64;
    if (tid < 64) {
        int m = m0 + tid;
        if (gidx) { int t = m >> 5, b = m & 31; toks[tid] = gidx[b * LAV + t]; }
        else toks[tid] = m;
    }
    __syncthreads();
    float acc[4][4] = {};
    int tx = tid & 15, ty = tid >> 4;
    for (int k0 = 0; k0 < K; k0 += 32) {
        {
            int r = tid >> 2, cc = (tid & 3) * 8;
            const float* src = X + (size_t)toks[r] * ldx + k0 + cc;
            float4 v0 = {0.f,0.f,0.f,0.f}, v1 = {0.f,0.f,0.f,0.f};
            if (k0 + cc + 3 < K) v0 = *(const float4*)src;
            if (k0 + cc + 7 < K) v1 = *(const float4*)(src + 4);
            As[cc+0][r]=v0.x; As[cc+1][r]=v0.y; As[cc+2][r]=v0.z; As[cc+3][r]=v0.w;
            As[cc+4][r]=v1.x; As[cc+5][r]=v1.y; As[cc+6][r]=v1.z; As[cc+7][r]=v1.w;
        }
        {
            int kr = tid >> 4, c4 = (tid & 15) * 4;
            #pragma unroll
            for (int p = 0; p < 2; ++p) {
                float4 v = {0.f,0.f,0.f,0.f};
                int kg = k0 + kr + p * 16;
                if (kg < K) v = *(const float4*)(Wt + (size_t)kg * Nn + n0 + c4);
                *(float4*)&Bs[kr + p * 16][c4] = v;
            }
        }
        __syncthreads();
        #pragma unroll 8
        for (int kk = 0; kk < 32; ++kk) {
            float4 a4 = *(const float4*)&As[kk][ty * 4];
            float4 b4 = *(const float4*)&Bs[kk][tx * 4];
            acc[0][0]=fmaf(a4.x,b4.x,acc[0][0]); acc[0][1]=fmaf(a4.x,b4.y,acc[0][1]);
            acc[0][2]=fmaf(a4.x,b4.z,acc[0][2]); acc[0][3]=fmaf(a4.x,b4.w,acc[0][3]);
            acc[1][0]=fmaf(a4.y,b4.x,acc[1][0]); acc[1][1]=fmaf(a4.y,b4.y,acc[1][1]);
            acc[1][2]=fmaf(a4.y,b4.z,acc[1][2]); acc[1][3]=fmaf(a4.y,b4.w,acc[1][3]);
            acc[2][0]=fmaf(a4.z,b4.x,acc[2][0]); acc[2][1]=fmaf(a4.z,b4.y,acc[2][1]);
            acc[2][2]=fmaf(a4.z,b4.z,acc[2][2]); acc[2][3]=fmaf(a4.z,b4.w,acc[2][3]);
            acc[3][0]=fmaf(a4.w,b4.x,acc[3][0]); acc[3][1]=fmaf(a4.w,b4.y,acc[3][1]);
            acc[3][2]=fmaf(a4.w,b4.z,acc[3][2]); acc[3][3]=fmaf(a4.w,b4.w,acc[3][3]);
        }
        __syncthreads();
    }
    if (MODE == 0) {
        float4 bz = *(const float4*)&bias[n0 + tx * 4];
        #pragma unroll
        for (int i = 0; i < 4; ++i) {
            int m = m0 + ty * 4 + i;
            float4 o = { acc[i][0] + bz.x, acc[i][1] + bz.y, acc[i][2] + bz.z, acc[i][3] + bz.w };
            *(float4*)&Cout[(size_t)m * Nn + n0 + tx * 4] = o;
        }
    } else {
        #pragma unroll
        for (int i = 0; i < 4; ++i) {
            int m = m0 + ty * 4 + i;
            int b_ = m >> 8, l = m & 255;
            int hb = n0 + tx * 4;
            Cout[((size_t)(b_ * 256 + hb + 0)) * 256 + l] = tanh_(acc[i][0]);
            Cout[((size_t)(b_ * 256 + hb + 1)) * 256 + l] = tanh_(acc[i][1]);
            Cout[((size_t)(b_ * 256 + hb + 2)) * 256 + l] = tanh_(acc[i][2]);
            Cout[((size_t)(b_ * 256 + hb + 3)) * 256 + l] = tanh_(acc[i][3]);
        }
    }
}

// ---------- anchor GRU: one WG per batch element (unchanged, fp32) ----------
__global__ __launch_bounds__(384) void anchor_rnn(
    const float* __restrict__ GI, const int* __restrict__ lens,
    const float* __restrict__ bhh, const float* __restrict__ Whh4,
    float* __restrict__ AO, float* __restrict__ hid, float* __restrict__ outp)
{
    int bid = blockIdx.x, tid = threadIdx.x;
    __shared__ __align__(16) float hs[256];
    __shared__ float gh[768];
    if (tid < 256) hs[tid] = 0.f;
    float sum = 0.f;
    int len = lens[bid];
    const float4* W4 = (const float4*)Whh4;
    const float4* hs4 = (const float4*)hs;
    __syncthreads();
    for (int t = 0; t < LAV; ++t) {
        {
            int j0 = tid, j1 = tid + 384;
            float a0=0.f,a1=0.f,a2=0.f,a3=0.f;
            #pragma unroll 8
            for (int k4 = 0; k4 < 64; ++k4) {
                float4 h4 = hs4[k4];
                float4 w0 = W4[k4 * 768 + j0];
                float4 w1 = W4[k4 * 768 + j1];
                a0=fmaf(w0.x,h4.x,a0); a1=fmaf(w0.y,h4.y,a1); a0=fmaf(w0.z,h4.z,a0); a1=fmaf(w0.w,h4.w,a1);
                a2=fmaf(w1.x,h4.x,a2); a3=fmaf(w1.y,h4.y,a3); a2=fmaf(w1.z,h4.z,a2); a3=fmaf(w1.w,h4.w,a3);
            }
            gh[j0] = a0 + a1 + bhh[j0];
            gh[j1] = a2 + a3 + bhh[j1];
        }
        __syncthreads();
        if (tid < 256) {
            const float* gi = GI + ((size_t)t * BB + bid) * G3;
            float gir = gi[tid], giz = gi[256 + tid], gin = gi[512 + tid];
            float r = sigm(gir + gh[tid]);
            float z = sigm(giz + gh[256 + tid]);
            float n = tanh_(fmaf(r, gh[512 + tid], gin));
            float hk = hs[tid];
            float hn = (1.f - z) * n + z * hk;
            bool valid = (t < len);
            float hnew = valid ? hn : hk;
            hs[tid] = hnew;
            float ov = valid ? hn : 0.f;
            AO[((size_t)bid * LAV + t) * HV + tid] = ov;
            sum += ov;
        }
        __syncthreads();
    }
    if (tid < 256) {
        outp[bid * HV + tid] = sum / (float)len;
        hid[bid * HV + tid] = hs[tid];
    }
}

// ---------- inter-WG barrier (8 WGs of one batch), device scope ----------
static __device__ __forceinline__ void arrive_wait(unsigned* cnt, unsigned target, unsigned* dead) {
    __threadfence();
    __syncthreads();
    if (threadIdx.x == 0) {
        __hip_atomic_fetch_add(cnt, 1u, __ATOMIC_RELEASE, __HIP_MEMORY_SCOPE_AGENT);
        unsigned it = 0;
        while (__hip_atomic_load(cnt, __ATOMIC_ACQUIRE, __HIP_MEMORY_SCOPE_AGENT) < target) {
            __builtin_amdgcn_s_sleep(1);
            if (((++it) & 0xFFFFu) == 0u) {
                if (__hip_atomic_load(dead, __ATOMIC_RELAXED, __HIP_MEMORY_SCOPE_AGENT)) break;
                if (it > (1u << 24)) { __hip_atomic_store(dead, 1u, __ATOMIC_RELAXED, __HIP_MEMORY_SCOPE_AGENT); break; }
            }
        }
    }
    __syncthreads();
    __threadfence();
}

// ---------- candidate GRU + attention: 8 WGs per batch, persistent LDS weights ----------
// Slice c owns h-dims [c*32, c*32+32). Per step:
//   P0 q slice (needs full h, local)  P1 score partials over h-slice -> BARRIER1
//   P2 softmax (redundant)  P3 ctx slice  P4 gate partials (k-split) -> BARRIER2
//   P5 gate reduce + h update (redundant on all 8 WGs; no h gather needed)
__global__ __launch_bounds__(512) void cand_rnn(
    const float* __restrict__ GI, const int* __restrict__ lens,
    const float* __restrict__ bhh, const __half* __restrict__ Wg_h,
    const __half* __restrict__ Wq_h, const float* __restrict__ v_att,
    const float* __restrict__ AO, const float* __restrict__ T,
    const float* __restrict__ hid, float* __restrict__ scoreP,
    float* __restrict__ gateP, unsigned* __restrict__ syncb,
    float* __restrict__ outp)
{
    __shared__ __align__(16) __half WgS[64 * 768];   // 96KB gate weight slice [k][j]
    __shared__ __align__(16) __half WqS[256 * 32];   // 16KB Wq slice [k][m]
    __shared__ __align__(16) __half TS[32 * 256];    // 16KB tanh(keys) slice [h][l]
    __shared__ __align__(16) __half AOS[256 * 32];   // 16KB AO slice [l][h]
    __shared__ __align__(16) float red[512];
    __shared__ float bhhS[768];
    __shared__ __align__(16) float hs[256];
    __shared__ float xs[32], tqs[32], vls[32], attn[256], wred[8];

    int tid = threadIdx.x;
    int bid = blockIdx.x;
    int b = bid & 31, c = bid >> 5;
    int len = lens[b];
    unsigned* cnt1 = syncb + b;
    unsigned* cnt2 = syncb + 32 + b;
    unsigned* dead = syncb + 64;

    { // persistent LDS loads
        const uint4* s1 = (const uint4*)(Wg_h + (size_t)c * 64 * 768);
        uint4* d1 = (uint4*)WgS;
        for (int i = tid; i < 64 * 768 / 8; i += 512) d1[i] = s1[i];
        const uint4* s2 = (const uint4*)(Wq_h + (size_t)c * 256 * 32);
        uint4* d2 = (uint4*)WqS;
        for (int i = tid; i < 256 * 32 / 8; i += 512) d2[i] = s2[i];
        __half2* dT = (__half2*)TS;
        for (int i = tid; i < 32 * 256 / 2; i += 512) {
            int hh = i >> 7, ll = (i & 127) * 2;
            float2 v = *(const float2*)&T[((size_t)(b * 256 + c * 32 + hh)) * 256 + ll];
            dT[i] = __half2{ __float2half(v.x), __float2half(v.y) };
        }
        __half2* dA = (__half2*)AOS;
        for (int i = tid; i < 256 * 32 / 2; i += 512) {
            int l = i >> 4, hp = (i & 15) * 2;
            float2 v = *(const float2*)&AO[((size_t)b * 256 + l) * 256 + c * 32 + hp];
            dA[i] = __half2{ __float2half(v.x), __float2half(v.y) };
        }
        for (int i = tid; i < 768; i += 512) bhhS[i] = bhh[i];
        if (tid < 256) hs[tid] = hid[b * 256 + tid];
        if (tid < 32) vls[tid] = v_att[c * 32 + tid];
    }
    __syncthreads();

    float csum = 0.f;
    const float* scorePb = scoreP + (size_t)b * 8 * 256;
    float* gpb = gateP + ((size_t)b * 8 + c) * 1024;

    for (int t = 0; t < LCV; ++t) {
        { // P0a: q partials (m = h-slice dims, k-chunked)
            int mm = tid & 31, kc = tid >> 5;
            float a = 0.f;
            #pragma unroll
            for (int i = 0; i < 16; ++i) {
                int k = kc * 16 + i;
                a = fmaf(hs[k], __half2float(WqS[k * 32 + mm]), a);
            }
            red[kc * 32 + mm] = a;
        }
        __syncthreads();
        if (tid < 32) { // P0b
            float q = 0.f;
            #pragma unroll
            for (int kc = 0; kc < 16; ++kc) q += red[kc * 32 + tid];
            tqs[tid] = tanh_(q);
        }
        __syncthreads();
        { // P1a: score partials: tanh(k+q) = (T+tq)/(1+T*tq)
            int l = tid & 255, hg = tid >> 8;
            float acc = 0.f;
            #pragma unroll
            for (int i = 0; i < 16; ++i) {
                int h = hg * 16 + i;
                float Tv = __half2float(TS[h * 256 + l]);
                float tq = tqs[h], vv = vls[h];
                float d = fmaf(Tv, tq, 1.f);
                acc = fmaf(vv * (Tv + tq), rcp_(fmaxf(d, 1e-30f)), acc);
            }
            red[hg * 256 + l] = acc;
        }
        __syncthreads();
        if (tid < 256) { // P1b: write score partial
            scoreP[((size_t)b * 8 + c) * 256 + tid] = red[tid] + red[256 + tid];
        }
        arrive_wait(cnt1, 8u * (unsigned)(t + 1), dead);
        float sv = 0.f;
        if (tid < 256) { // P2a: full scores (redundant) + wave max
            #pragma unroll
            for (int cc = 0; cc < 8; ++cc) sv += scorePb[cc * 256 + tid];
            float m = sv;
            #pragma unroll
            for (int o = 1; o < 64; o <<= 1) m = fmaxf(m, __shfl_xor(m, o, 64));
            if ((tid & 63) == 0) wred[tid >> 6] = m;
        }
        __syncthreads();
        if (tid < 256) { // P2b: exp + wave sum
            float mx = fmaxf(fmaxf(wred[0], wred[1]), fmaxf(wred[2], wred[3]));
            float e = __expf(sv - mx);
            attn[tid] = e;
            float s = e;
            #pragma unroll
            for (int o = 1; o < 64; o <<= 1) s += __shfl_xor(s, o, 64);
            if ((tid & 63) == 0) wred[4 + (tid >> 6)] = s;
        }
        __syncthreads();
        { // P3a: ctx partials over l-chunks
            int hp = tid & 31, lc = tid >> 5;
            float a = 0.f;
            #pragma unroll
            for (int i = 0; i < 16; ++i) {
                int l = lc * 16 + i;
                a = fmaf(attn[l], __half2float(AOS[l * 32 + hp]), a);
            }
            red[lc * 32 + hp] = a;
        }
        __syncthreads();
        if (tid < 32) { // P3b: finalize ctx slice
            float s = 0.f;
            #pragma unroll
            for (int lc = 0; lc < 16; ++lc) s += red[lc * 32 + tid];
            float sumv = wred[4] + wred[5] + wred[6] + wred[7];
            xs[tid] = s * rcp_(sumv);
        }
        __syncthreads();
        if (tid < 384) { // P4: gate partials, k-split over local [h-slice; ctx-slice]
            const __half2* W2 = (const __half2*)WgS;
            int hb = c * 32;
            float a0=0.f,a1=0.f,b0=0.f,b1=0.f;
            #pragma unroll 8
            for (int k = 0; k < 32; ++k) {
                float x = hs[hb + k];
                float2 w = __half22float2(W2[k * 384 + tid]);
                a0 = fmaf(x, w.x, a0); a1 = fmaf(x, w.y, a1);
            }
            #pragma unroll 8
            for (int k = 0; k < 32; ++k) {
                float x = xs[k];
                float2 w = __half22float2(W2[(k + 32) * 384 + tid]);
                b0 = fmaf(x, w.x, b0); b1 = fmaf(x, w.y, b1);
            }
            if (tid < 256) {       // r,z rows: merged over all k
                *(float2*)&gpb[2 * tid] = make_float2(a0 + b0, a1 + b1);
            } else {               // n rows: keep hidden-part and ctx-part separate
                int jp = 2 * (tid - 256);
                *(float2*)&gpb[512 + jp] = make_float2(a0, a1);
                *(float2*)&gpb[768 + jp] = make_float2(b0, b1);
            }
        }
        arrive_wait(cnt2, 8u * (unsigned)(t + 1), dead);
        if (tid < 256) { // P5: reduce gates + GRU update (redundant on all 8 WGs)
            const float* gi = GI + ((size_t)t * BB + b) * G3;
            float rr = 0.f, zz = 0.f, nh = 0.f, nc = 0.f;
            #pragma unroll
            for (int cc = 0; cc < 8; ++cc) {
                const float* gp = gateP + ((size_t)b * 8 + cc) * 1024;
                rr += gp[tid]; zz += gp[256 + tid]; nh += gp[512 + tid]; nc += gp[768 + tid];
            }
            float r = sigm(gi[tid] + rr + bhhS[tid]);
            float z = sigm(gi[256 + tid] + zz + bhhS[256 + tid]);
            float n = tanh_(gi[512 + tid] + nc + r * (nh + bhhS[512 + tid]));
            float hk = hs[tid];
            float hn = (1.f - z) * n + z * hk;
            float hnew = (len < t) ? hk : hn;
            hs[tid] = hnew;
            if (t < len) csum += hnew;
        }
        __syncthreads();
    }
    if (c == 0 && tid < 256) outp[8192 + b * 256 + tid] = csum / (float)len;
}

extern "C" void kernel_launch(void* const* d_in, const int* in_sizes, int n_in,
                              void* d_out, int out_size, void* d_ws, size_t ws_size,
                              hipStream_t stream) {
    const int* anchor_input     = (const int*)d_in[0];
    const int* anchor_length    = (const int*)d_in[1];
    const int* candidate_input  = (const int*)d_in[2];
    const int* candidate_length = (const int*)d_in[3];
    const float* emb    = (const float*)d_in[5];
    const float* W_ih_a = (const float*)d_in[6];
    const float* W_hh_a = (const float*)d_in[7];
    const float* b_ih_a = (const float*)d_in[8];
    const float* b_hh_a = (const float*)d_in[9];
    const float* W_ih_c = (const float*)d_in[10];
    const float* W_hh_c = (const float*)d_in[11];
    const float* b_ih_c = (const float*)d_in[12];
    const float* b_hh_c = (const float*)d_in[13];
    const float* Wq     = (const float*)d_in[14];
    const float* Wk     = (const float*)d_in[15];
    const float* v_att  = (const float*)d_in[16];
    float* out = (float*)d_out;

    // workspace layout (float units)
    float* ws = (float*)d_ws;
    size_t off = 0;
    float* GI_a  = ws + off; off += (size_t)LAV * BB * G3;     // 6291456
    float* GI_c  = ws + off; off += (size_t)LCV * BB * G3;     // 6291456
    float* AO    = ws + off; off += (size_t)BB * LAV * HV;     // 2097152
    float* T     = ws + off; off += (size_t)BB * HV * LAV;     // 2097152  [b][h][l]
    float* hid   = ws + off; off += (size_t)BB * HV;           // 8192
    float* WT_a  = ws + off; off += 300 * 768;                 // 230400 (dead after gemms)
    float* WT_cx = ws + off; off += 300 * 768;                 // 230400 (dead after gemms)
    float* Whha4 = ws + off; off += 64 * 768 * 4;              // 196608
    __half* Wq_h = (__half*)(ws + off); off += 8 * 256 * 32 / 2;   // 65536 halves
    __half* Wg_h = (__half*)(ws + off); off += 8 * 64 * 768 / 2;   // 393216 halves
    // alias cand-phase buffers onto the (then-dead) WT_a/WT_cx region
    float* scoreP = WT_a;                          // 32*8*256 = 65536
    float* gateP  = WT_a + 65536;                  // 32*8*1024 = 262144
    unsigned* syncb = (unsigned*)(WT_a + 65536 + 262144);  // 80 uints

    prep_pack<<<dim3(1536, 5), 256, 0, stream>>>(W_ih_a, W_ih_c, W_hh_a, W_hh_c, Wq,
                                                 WT_a, WT_cx, Whha4, Wq_h, Wg_h);
    gemm_tile<0><<<dim3(128, 12), 256, 0, stream>>>(emb, anchor_input, DV, WT_a, DV, G3, b_ih_a, GI_a);
    gemm_tile<0><<<dim3(128, 12), 256, 0, stream>>>(emb, candidate_input, DV, WT_cx, DV, G3, b_ih_c, GI_c);
    anchor_rnn<<<32, 384, 0, stream>>>(GI_a, anchor_length, b_hh_a, Whha4, AO, hid, out);
    gemm_tile<1><<<dim3(128, 4), 256, 0, stream>>>(AO, nullptr, HV, Wk, HV, HV, nullptr, T);
    zero_sync<<<1, 128, 0, stream>>>(syncb);
    cand_rnn<<<256, 512, 0, stream>>>(GI_c, candidate_length, b_hh_c, Wg_h, Wq_h,
                                      v_att, AO, T, hid, scoreP, gateP, syncb, out);
}

// Round 3
// 5495.346 us; speedup vs baseline: 6.7138x; 6.7138x over previous
//
#include <hip/hip_runtime.h>
#include <hip/hip_fp16.h>
#include <math.h>

#define BB 32
#define LAV 256
#define LCV 256
#define DV 300
#define HV 256
#define G3 768   // 3*H

typedef _Float16 f16x2 __attribute__((ext_vector_type(2)));

// ---------- fast math helpers ----------
static __device__ __forceinline__ float rcp_(float x) { return __builtin_amdgcn_rcpf(x); }
static __device__ __forceinline__ float sigm(float x) { return rcp_(1.f + __expf(-x)); }
static __device__ __forceinline__ float tanh_(float x) { return 1.f - 2.f * rcp_(1.f + __expf(2.f * x)); }

// ---------- weight packing ----------
// case0: WT_a  [300][768] = W_ih_a^T                       (fp32, for GI gemm)
// case1: WT_cx [300][768] = W_ih_c[:, :300]^T              (fp32, for GI gemm)
// case2: Whha4 [64][768][4] fp32 quad-k pack of W_hh_a^T   (anchor)
// case3: WqH   half2[128 k2][256 m]  = {Wq[2k2][m], Wq[2k2+1][m]}
// case4: WrzH  half2[256 kk][512 j]: kk=kh*128+k2i, k=kh*256+2k2i+e
//        W[k][j] = k<256 ? W_hh_c[j][k] : W_ih_c[j][300+(k-256)]   (r,z rows j<512)
// case5: WnH   half2[256 gg][256 j]: gg=slot*64+k2i, slot=(grp<<1)|kh, kl=kh*128+2k2i+e
//        grp0: W_hh_c[512+j][kl]  grp1: W_ih_c[512+j][300+kl]      (n rows)
__global__ void prep_pack(const float* __restrict__ W_ih_a, const float* __restrict__ W_ih_c,
                          const float* __restrict__ W_hh_a, const float* __restrict__ W_hh_c,
                          const float* __restrict__ Wq,
                          float* __restrict__ WT_a, float* __restrict__ WT_cx,
                          float* __restrict__ Whha4, __half* __restrict__ WqH,
                          __half* __restrict__ WrzH, __half* __restrict__ WnH)
{
    int i = blockIdx.x * 256 + threadIdx.x;
    switch (blockIdx.y) {
    case 0: if (i < 300 * 768) { int k = i / 768, n = i % 768; WT_a[i] = W_ih_a[n * 300 + k]; } break;
    case 1: if (i < 300 * 768) { int k = i / 768, n = i % 768; WT_cx[i] = W_ih_c[n * 556 + k]; } break;
    case 2: if (i < 64 * 768 * 4) { int cc = i & 3, j = (i >> 2) % 768, k4 = (i >> 2) / 768;
            Whha4[i] = W_hh_a[j * 256 + k4 * 4 + cc]; } break;
    case 3: if (i < 65536) { int e = i & 1, r2 = i >> 1, m = r2 & 255, k2 = r2 >> 8;
            WqH[i] = __float2half(Wq[(2 * k2 + e) * 256 + m]); } break;
    case 4: if (i < 262144) { int e = i & 1, r2 = i >> 1, j = r2 & 511, kk = r2 >> 9;
            int kh = kk >> 7, k2i = kk & 127, k = kh * 256 + 2 * k2i + e;
            float v = (k < 256) ? W_hh_c[j * 256 + k] : W_ih_c[j * 556 + 300 + (k - 256)];
            WrzH[i] = __float2half(v); } break;
    case 5: if (i < 131072) { int e = i & 1, r2 = i >> 1, j = r2 & 255, gg = r2 >> 8;
            int slot = gg >> 6, k2i = gg & 63, grp = slot >> 1, kh = slot & 1;
            int kl = kh * 128 + 2 * k2i + e;
            float v = grp ? W_ih_c[(512 + j) * 556 + 300 + kl] : W_hh_c[(512 + j) * 256 + kl];
            WnH[i] = __float2half(v); } break;
    }
}

// ---------- tiled fp32 GEMM ----------
// MODE 0: Cout[m*N+n] = acc + bias[n]                       (GI precompute)
// MODE 1: TH half2[b][h][l2] = {tanh(acc@l), tanh(acc@l+1)} (keys -> T)
template <int MODE>
__global__ __launch_bounds__(256) void gemm_tile(
    const float* __restrict__ X, const int* __restrict__ gidx, int ldx,
    const float* __restrict__ Wt, int K, int Nn,
    const float* __restrict__ bias, float* __restrict__ Cout)
{
    __shared__ __align__(16) float As[32][68];
    __shared__ __align__(16) float Bs[32][68];
    __shared__ int toks[64];
    int tid = threadIdx.x;
    int m0 = blockIdx.x * 64, n0 = blockIdx.y * 64;
    if (tid < 64) {
        int m = m0 + tid;
        if (gidx) { int t = m >> 5, b = m & 31; toks[tid] = gidx[b * LAV + t]; }
        else toks[tid] = m;
    }
    __syncthreads();
    float acc[4][4] = {};
    int tx = tid & 15, ty = tid >> 4;
    for (int k0 = 0; k0 < K; k0 += 32) {
        {
            int r = tid >> 2, cc = (tid & 3) * 8;
            const float* src = X + (size_t)toks[r] * ldx + k0 + cc;
            float4 v0 = {0.f,0.f,0.f,0.f}, v1 = {0.f,0.f,0.f,0.f};
            if (k0 + cc + 3 < K) v0 = *(const float4*)src;
            if (k0 + cc + 7 < K) v1 = *(const float4*)(src + 4);
            As[cc+0][r]=v0.x; As[cc+1][r]=v0.y; As[cc+2][r]=v0.z; As[cc+3][r]=v0.w;
            As[cc+4][r]=v1.x; As[cc+5][r]=v1.y; As[cc+6][r]=v1.z; As[cc+7][r]=v1.w;
        }
        {
            int kr = tid >> 4, c4 = (tid & 15) * 4;
            #pragma unroll
            for (int p = 0; p < 2; ++p) {
                float4 v = {0.f,0.f,0.f,0.f};
                int kg = k0 + kr + p * 16;
                if (kg < K) v = *(const float4*)(Wt + (size_t)kg * Nn + n0 + c4);
                *(float4*)&Bs[kr + p * 16][c4] = v;
            }
        }
        __syncthreads();
        #pragma unroll 8
        for (int kk = 0; kk < 32; ++kk) {
            float4 a4 = *(const float4*)&As[kk][ty * 4];
            float4 b4 = *(const float4*)&Bs[kk][tx * 4];
            acc[0][0]=fmaf(a4.x,b4.x,acc[0][0]); acc[0][1]=fmaf(a4.x,b4.y,acc[0][1]);
            acc[0][2]=fmaf(a4.x,b4.z,acc[0][2]); acc[0][3]=fmaf(a4.x,b4.w,acc[0][3]);
            acc[1][0]=fmaf(a4.y,b4.x,acc[1][0]); acc[1][1]=fmaf(a4.y,b4.y,acc[1][1]);
            acc[1][2]=fmaf(a4.y,b4.z,acc[1][2]); acc[1][3]=fmaf(a4.y,b4.w,acc[1][3]);
            acc[2][0]=fmaf(a4.z,b4.x,acc[2][0]); acc[2][1]=fmaf(a4.z,b4.y,acc[2][1]);
            acc[2][2]=fmaf(a4.z,b4.z,acc[2][2]); acc[2][3]=fmaf(a4.z,b4.w,acc[2][3]);
            acc[3][0]=fmaf(a4.w,b4.x,acc[3][0]); acc[3][1]=fmaf(a4.w,b4.y,acc[3][1]);
            acc[3][2]=fmaf(a4.w,b4.z,acc[3][2]); acc[3][3]=fmaf(a4.w,b4.w,acc[3][3]);
        }
        __syncthreads();
    }
    if (MODE == 0) {
        float4 bz = *(const float4*)&bias[n0 + tx * 4];
        #pragma unroll
        for (int i = 0; i < 4; ++i) {
            int m = m0 + ty * 4 + i;
            float4 o = { acc[i][0] + bz.x, acc[i][1] + bz.y, acc[i][2] + bz.z, acc[i][3] + bz.w };
            *(float4*)&Cout[(size_t)m * Nn + n0 + tx * 4] = o;
        }
    } else {
        int b_ = m0 >> 8;
        int l0 = (m0 & 255) + ty * 4;
        f16x2* TH = (f16x2*)Cout;
        #pragma unroll
        for (int j = 0; j < 4; ++j) {
            int h = n0 + tx * 4 + j;
            size_t base = ((size_t)(b_ * 256 + h)) * 128 + (l0 >> 1);
            f16x2 v01 = { (_Float16)tanh_(acc[0][j]), (_Float16)tanh_(acc[1][j]) };
            f16x2 v23 = { (_Float16)tanh_(acc[2][j]), (_Float16)tanh_(acc[3][j]) };
            TH[base] = v01;
            TH[base + 1] = v23;
        }
    }
}

// ---------- anchor GRU: one WG per batch element (fp32) ----------
__global__ __launch_bounds__(384) void anchor_rnn(
    const float* __restrict__ GI, const int* __restrict__ lens,
    const float* __restrict__ bhh, const float* __restrict__ Whh4,
    float* __restrict__ AO, __half* __restrict__ AOH,
    float* __restrict__ hid, float* __restrict__ outp)
{
    int bid = blockIdx.x, tid = threadIdx.x;
    __shared__ __align__(16) float hs[256];
    __shared__ float gh[768];
    if (tid < 256) hs[tid] = 0.f;
    float sum = 0.f;
    int len = lens[bid];
    const float4* W4 = (const float4*)Whh4;
    const float4* hs4 = (const float4*)hs;
    __syncthreads();
    for (int t = 0; t < LAV; ++t) {
        {
            int j0 = tid, j1 = tid + 384;
            float a0=0.f,a1=0.f,a2=0.f,a3=0.f;
            #pragma unroll 8
            for (int k4 = 0; k4 < 64; ++k4) {
                float4 h4 = hs4[k4];
                float4 w0 = W4[k4 * 768 + j0];
                float4 w1 = W4[k4 * 768 + j1];
                a0=fmaf(w0.x,h4.x,a0); a1=fmaf(w0.y,h4.y,a1); a0=fmaf(w0.z,h4.z,a0); a1=fmaf(w0.w,h4.w,a1);
                a2=fmaf(w1.x,h4.x,a2); a3=fmaf(w1.y,h4.y,a3); a2=fmaf(w1.z,h4.z,a2); a3=fmaf(w1.w,h4.w,a3);
            }
            gh[j0] = a0 + a1 + bhh[j0];
            gh[j1] = a2 + a3 + bhh[j1];
        }
        __syncthreads();
        if (tid < 256) {
            const float* gi = GI + ((size_t)t * BB + bid) * G3;
            float gir = gi[tid], giz = gi[256 + tid], gin = gi[512 + tid];
            float r = sigm(gir + gh[tid]);
            float z = sigm(giz + gh[256 + tid]);
            float n = tanh_(fmaf(r, gh[512 + tid], gin));
            float hk = hs[tid];
            float hn = (1.f - z) * n + z * hk;
            bool valid = (t < len);
            float hnew = valid ? hn : hk;
            hs[tid] = hnew;
            float ov = valid ? hn : 0.f;
            AO[((size_t)bid * LAV + t) * HV + tid] = ov;
            AOH[((size_t)bid * LAV + t) * HV + tid] = __float2half(ov);
            sum += ov;
        }
        __syncthreads();
    }
    if (tid < 256) {
        outp[bid * HV + tid] = sum / (float)len;
        hid[bid * HV + tid] = hs[tid];
    }
}

// ---------- candidate GRU + attention: one WG per batch, fp16 weights, fdot2 ----------
__global__ __launch_bounds__(1024) void cand_rnn(
    const float* __restrict__ GI, const int* __restrict__ lens,
    const float* __restrict__ bhh, const __half* __restrict__ WrzH,
    const __half* __restrict__ WnH, const __half* __restrict__ WqH,
    const float* __restrict__ v_att, const __half* __restrict__ AOH,
    const __half* __restrict__ TH, const float* __restrict__ hid,
    float* __restrict__ outp)
{
    __shared__ __align__(16) f16x2 x2[256];   // [h pairs(128); ctx pairs(128)]
    __shared__ __align__(16) float hs[256];
    __shared__ float tqs[256];
    __shared__ float vls[256];
    __shared__ float attn[256];
    __shared__ __align__(16) float red[3072];
    __shared__ float bhhS[768];
    __shared__ float wred[8];

    int tid = threadIdx.x;
    int b = blockIdx.x;
    int len = lens[b];

    const f16x2* Wq2  = (const f16x2*)WqH;
    const f16x2* Wrz2 = (const f16x2*)WrzH;
    const f16x2* Wn2  = (const f16x2*)WnH;
    const f16x2* T2   = (const f16x2*)TH + (size_t)b * 256 * 128;
    const f16x2* AO2  = (const f16x2*)AOH + (size_t)b * 256 * 128;

    if (tid < 256) { hs[tid] = hid[b * HV + tid]; vls[tid] = v_att[tid]; }
    if (tid < 768) bhhS[tid] = bhh[tid];
    __syncthreads();
    if (tid < 128) {
        f16x2 v = { (_Float16)hs[2 * tid], (_Float16)hs[2 * tid + 1] };
        x2[tid] = v;
    }
    __syncthreads();

    float csum = 0.f;

    for (int t = 0; t < LCV; ++t) {
        { // P0: q partials, 4-way k-split: q[m] = sum_k h[k] Wq[k][m]
            int m = tid & 255, kc = tid >> 8;
            float a0 = 0.f, a1 = 0.f;
            #pragma unroll 8
            for (int i = 0; i < 32; i += 2) {
                int k2 = kc * 32 + i;
                a0 = __builtin_amdgcn_fdot2(Wq2[k2 * 256 + m], x2[k2], a0, false);
                a1 = __builtin_amdgcn_fdot2(Wq2[(k2 + 1) * 256 + m], x2[k2 + 1], a1, false);
            }
            red[kc * 256 + m] = a0 + a1;
        }
        __syncthreads();
        if (tid < 256) { // P0b: tq = tanh(q)
            float q = red[tid] + red[256 + tid] + red[512 + tid] + red[768 + tid];
            tqs[tid] = tanh_(q);
        }
        __syncthreads();
        { // P1: score partials: tanh(k+q) = (T+tq)/(1+T*tq)
            int l2 = tid & 127, hg = tid >> 7;
            float s0 = 0.f, s1 = 0.f;
            #pragma unroll 8
            for (int i = 0; i < 32; ++i) {
                int h = hg * 32 + i;
                f16x2 Tv = T2[(size_t)h * 128 + l2];
                float tq = tqs[h], vv = vls[h];
                float T0 = (float)Tv.x, T1 = (float)Tv.y;
                float d0 = fmaxf(fmaf(T0, tq, 1.f), 1e-6f);
                float d1 = fmaxf(fmaf(T1, tq, 1.f), 1e-6f);
                s0 = fmaf(vv * (T0 + tq), rcp_(d0), s0);
                s1 = fmaf(vv * (T1 + tq), rcp_(d1), s1);
            }
            red[hg * 256 + 2 * l2] = s0;
            red[hg * 256 + 2 * l2 + 1] = s1;
        }
        __syncthreads();
        float sv = 0.f;
        if (tid < 256) { // P2a: reduce 8 partials + wave max
            #pragma unroll
            for (int hg = 0; hg < 8; ++hg) sv += red[hg * 256 + tid];
            float m = sv;
            #pragma unroll
            for (int o = 1; o < 64; o <<= 1) m = fmaxf(m, __shfl_xor(m, o, 64));
            if ((tid & 63) == 0) wred[tid >> 6] = m;
        }
        __syncthreads();
        if (tid < 256) { // P2b: exp + wave sum
            float mx = fmaxf(fmaxf(wred[0], wred[1]), fmaxf(wred[2], wred[3]));
            float e = __expf(sv - mx);
            attn[tid] = e;
            float s = e;
            #pragma unroll
            for (int o = 1; o < 64; o <<= 1) s += __shfl_xor(s, o, 64);
            if ((tid & 63) == 0) wred[4 + (tid >> 6)] = s;
        }
        __syncthreads();
        { // P3: ctx partials, 8-way l-split
            int ho2 = tid & 127, lc = tid >> 7;
            float c0 = 0.f, c1 = 0.f;
            #pragma unroll 8
            for (int i = 0; i < 32; ++i) {
                int l = lc * 32 + i;
                f16x2 ao = AO2[(size_t)l * 128 + ho2];
                float w = attn[l];
                c0 = fmaf(w, (float)ao.x, c0);
                c1 = fmaf(w, (float)ao.y, c1);
            }
            red[lc * 256 + 2 * ho2] = c0;
            red[lc * 256 + 2 * ho2 + 1] = c1;
        }
        __syncthreads();
        if (tid < 128) { // P3b: finalize ctx pair -> x2[128+]
            float c0 = 0.f, c1 = 0.f;
            #pragma unroll
            for (int lc = 0; lc < 8; ++lc) {
                c0 += red[lc * 256 + 2 * tid];
                c1 += red[lc * 256 + 2 * tid + 1];
            }
            float rs = rcp_(wred[4] + wred[5] + wred[6] + wred[7]);
            f16x2 v = { (_Float16)(c0 * rs), (_Float16)(c1 * rs) };
            x2[128 + tid] = v;
        }
        __syncthreads();
        { // P4A: r,z gates, 2-way k-split: 1024 tasks x 128 fdot2
            int j = tid & 511, kh = tid >> 9;
            float a0 = 0.f, a1 = 0.f;
            #pragma unroll 8
            for (int i = 0; i < 128; i += 2) {
                int kk = kh * 128 + i;
                a0 = __builtin_amdgcn_fdot2(Wrz2[(size_t)kk * 512 + j], x2[kk], a0, false);
                a1 = __builtin_amdgcn_fdot2(Wrz2[(size_t)(kk + 1) * 512 + j], x2[kk + 1], a1, false);
            }
            red[tid] = a0 + a1;
        }
        { // P4B: n gates (hidden / ctx), 2-way k-split: 1024 tasks x 64 fdot2
            int j = tid & 255, slot = tid >> 8;       // slot = (grp<<1)|kh
            int grp = slot >> 1, kh = slot & 1;
            int xb = grp * 128 + kh * 64;
            float a0 = 0.f, a1 = 0.f;
            #pragma unroll 8
            for (int i = 0; i < 64; i += 2) {
                int gg = slot * 64 + i;
                a0 = __builtin_amdgcn_fdot2(Wn2[(size_t)gg * 256 + j], x2[xb + i], a0, false);
                a1 = __builtin_amdgcn_fdot2(Wn2[(size_t)(gg + 1) * 256 + j], x2[xb + i + 1], a1, false);
            }
            red[1024 + tid] = a0 + a1;
        }
        __syncthreads();
        if (tid < 256) { // P5: gate reduce + GRU update
            const float* gi = GI + ((size_t)t * BB + b) * G3;
            float rr = red[tid] + red[512 + tid];
            float zz = red[256 + tid] + red[768 + tid];
            float nh = red[1024 + tid] + red[1280 + tid];
            float nc = red[1536 + tid] + red[1792 + tid];
            float r = sigm(gi[tid] + rr + bhhS[tid]);
            float z = sigm(gi[256 + tid] + zz + bhhS[256 + tid]);
            float n = tanh_(gi[512 + tid] + nc + r * (nh + bhhS[512 + tid]));
            float hk = hs[tid];
            float hn = (1.f - z) * n + z * hk;
            float hnew = (len < t) ? hk : hn;        // strict '<' per reference
            hs[tid] = hnew;
            if (t < len) csum += hnew;
            // rebuild h half2 pairs via shfl (lane pairs within a wave)
            float other = __shfl_xor(hnew, 1, 64);
            if ((tid & 1) == 0) {
                f16x2 v = { (_Float16)hnew, (_Float16)other };
                x2[tid >> 1] = v;
            }
        }
        __syncthreads();
    }
    if (tid < 256) outp[8192 + b * HV + tid] = csum / (float)len;
}

extern "C" void kernel_launch(void* const* d_in, const int* in_sizes, int n_in,
                              void* d_out, int out_size, void* d_ws, size_t ws_size,
                              hipStream_t stream) {
    const int* anchor_input     = (const int*)d_in[0];
    const int* anchor_length    = (const int*)d_in[1];
    const int* candidate_input  = (const int*)d_in[2];
    const int* candidate_length = (const int*)d_in[3];
    const float* emb    = (const float*)d_in[5];
    const float* W_ih_a = (const float*)d_in[6];
    const float* W_hh_a = (const float*)d_in[7];
    const float* b_ih_a = (const float*)d_in[8];
    const float* b_hh_a = (const float*)d_in[9];
    const float* W_ih_c = (const float*)d_in[10];
    const float* W_hh_c = (const float*)d_in[11];
    const float* b_ih_c = (const float*)d_in[12];
    const float* b_hh_c = (const float*)d_in[13];
    const float* Wq     = (const float*)d_in[14];
    const float* Wk     = (const float*)d_in[15];
    const float* v_att  = (const float*)d_in[16];
    float* out = (float*)d_out;

    // workspace layout (float units), ~70.7 MB total
    float* ws = (float*)d_ws;
    size_t off = 0;
    float* GI_a  = ws + off; off += (size_t)LAV * BB * G3;     // 6291456
    float* GI_c  = ws + off; off += (size_t)LCV * BB * G3;     // 6291456
    float* AO    = ws + off; off += (size_t)BB * LAV * HV;     // 2097152
    float* hid   = ws + off; off += (size_t)BB * HV;           // 8192
    float* WT_a  = ws + off; off += 300 * 768;                 // 230400
    float* WT_cx = ws + off; off += 300 * 768;                 // 230400
    float* Whha4 = ws + off; off += 64 * 768 * 4;              // 196608
    __half* TH   = (__half*)(ws + off); off += (size_t)BB * HV * LAV / 2;  // 1048576 fl
    __half* AOH  = (__half*)(ws + off); off += (size_t)BB * LAV * HV / 2;  // 1048576 fl
    __half* WqH  = (__half*)(ws + off); off += 65536 / 2;      // 32768 fl
    __half* WrzH = (__half*)(ws + off); off += 262144 / 2;     // 131072 fl
    __half* WnH  = (__half*)(ws + off); off += 131072 / 2;     // 65536 fl

    prep_pack<<<dim3(1024, 6), 256, 0, stream>>>(W_ih_a, W_ih_c, W_hh_a, W_hh_c, Wq,
                                                 WT_a, WT_cx, Whha4, WqH, WrzH, WnH);
    gemm_tile<0><<<dim3(128, 12), 256, 0, stream>>>(emb, anchor_input, DV, WT_a, DV, G3, b_ih_a, GI_a);
    gemm_tile<0><<<dim3(128, 12), 256, 0, stream>>>(emb, candidate_input, DV, WT_cx, DV, G3, b_ih_c, GI_c);
    anchor_rnn<<<32, 384, 0, stream>>>(GI_a, anchor_length, b_hh_a, Whha4, AO, AOH, hid, out);
    gemm_tile<1><<<dim3(128, 4), 256, 0, stream>>>(AO, nullptr, HV, Wk, HV, HV, nullptr, (float*)TH);
    cand_rnn<<<32, 1024, 0, stream>>>(GI_c, candidate_length, b_hh_c, WrzH, WnH, WqH,
                                      v_att, AOH, TH, hid, out);
}